// Round 18
// baseline (1993.190 us; speedup 1.0000x reference)
//
#include <hip/hip_runtime.h>
#include <math.h>

#define TT 1024
#define DD 128
#define UU 64

__device__ __forceinline__ float sigm(float x) {
    return __builtin_amdgcn_rcpf(1.0f + __expf(-x));
}
__device__ __forceinline__ float tanhfast(float x) {
    float e = __expf(2.0f * x);
    return fmaf(-2.0f, __builtin_amdgcn_rcpf(e + 1.0f), 1.0f);
}

// DPP-based full-wave (64-lane) sum, result broadcast via readlane(63).
template<int CTRL>
__device__ __forceinline__ float dpp_add(float v) {
    return v + __int_as_float(__builtin_amdgcn_update_dpp(
        0, __float_as_int(v), CTRL, 0xf, 0xf, true));
}
__device__ __forceinline__ float wave_red_sum(float v) {
    v = dpp_add<0x111>(v);   // row_shr:1
    v = dpp_add<0x112>(v);   // row_shr:2
    v = dpp_add<0x114>(v);   // row_shr:4
    v = dpp_add<0x118>(v);   // row_shr:8
    v = dpp_add<0x142>(v);   // row_bcast:15
    v = dpp_add<0x143>(v);   // row_bcast:31
    return __int_as_float(__builtin_amdgcn_readlane(__float_as_int(v), 63));
}

// 64-float dot: LDS h-vector (wave-uniform broadcast float4 reads) x
// register-resident weight array (unroll-constant indices).
#define DOT64(res, vptr, WARR) do {                                \
    const float4* _v4 = (const float4*)(vptr);                     \
    float _a0 = 0.f, _a1 = 0.f, _a2 = 0.f, _a3 = 0.f;              \
    _Pragma("unroll")                                              \
    for (int _k = 0; _k < UU / 4; ++_k) {                          \
        float4 _hv = _v4[_k];                                      \
        _a0 = fmaf(_hv.x, WARR[4 * _k + 0], _a0);                  \
        _a1 = fmaf(_hv.y, WARR[4 * _k + 1], _a1);                  \
        _a2 = fmaf(_hv.z, WARR[4 * _k + 2], _a2);                  \
        _a3 = fmaf(_hv.w, WARR[4 * _k + 3], _a3);                  \
    }                                                              \
    res = (_a0 + _a1) + (_a2 + _a3);                               \
} while (0)

// ================= x-part GEMM (round-4 proven version) ======================
__global__ __launch_bounds__(256, 1)
void xgemm(const float* __restrict__ obss, const float* __restrict__ W1,
           float* __restrict__ z1x, int t0, int chsh)
{
    const int tid = threadIdx.x;
    const int CH = 1 << chsh;
    __shared__ __align__(16) float xs[64 * DD];

    const int rbase = blockIdx.x * 64;
    for (int i = tid; i < 64 * (DD / 4); i += 256) {
        int rr = i >> 5;
        int k4 = i & 31;
        int r  = rbase + rr;
        int b  = r >> chsh;
        int tl = r & (CH - 1);
        ((float4*)xs)[rr * 32 + k4] =
            ((const float4*)(obss + ((size_t)b * TT + t0 + tl) * DD))[k4];
    }

    float w[DD];
    #pragma unroll
    for (int k = 0; k < DD; ++k) w[k] = W1[k * 256 + tid];
    __syncthreads();

    for (int rr = 0; rr < 64; rr += 2) {
        float a0=0,a1=0,a2=0,a3=0, b0=0,b1=0,b2=0,b3=0;
        const float4* x0 = (const float4*)(xs + rr * DD);
        const float4* x1 = (const float4*)(xs + (rr + 1) * DD);
        #pragma unroll
        for (int k4 = 0; k4 < DD / 4; ++k4) {
            float4 xv = x0[k4], yv = x1[k4];
            a0 = fmaf(xv.x, w[4*k4+0], a0);
            a1 = fmaf(xv.y, w[4*k4+1], a1);
            a2 = fmaf(xv.z, w[4*k4+2], a2);
            a3 = fmaf(xv.w, w[4*k4+3], a3);
            b0 = fmaf(yv.x, w[4*k4+0], b0);
            b1 = fmaf(yv.y, w[4*k4+1], b1);
            b2 = fmaf(yv.z, w[4*k4+2], b2);
            b3 = fmaf(yv.w, w[4*k4+3], b3);
        }
        size_t r = (size_t)rbase + rr;
        z1x[r * 256 + tid]       = (a0 + a1) + (a2 + a3);
        z1x[(r + 1) * 256 + tid] = (b0 + b1) + (b2 + b3);
    }
}

// ========== recurrent kernel: monolithic 256 threads, weights in VGPRs =======
// R5-R17 lesson: only 256-thread blocks with __launch_bounds__(256,1) hoist
// weight arrays into registers (xgemm: 128 floats every round; R1: 204).
// All three recurrent matrices (w1h, w2x, w2h = 192 floats/thread) live in
// VGPRs -> ZERO per-step weight memory traffic (was 192 KB/CU/step, the
// R9-R17 ~1200us floor). 4 phases, 2 barriers/step, all-wave redundant cells.
__global__ __launch_bounds__(256, 1)
void lstm_rec(const float* __restrict__ z1x,
              const float* __restrict__ W1, const float* __restrict__ W2,
              const float* __restrict__ gamma1, const float* __restrict__ beta1,
              const float* __restrict__ gc1, const float* __restrict__ bc1,
              const float* __restrict__ gamma2, const float* __restrict__ beta2,
              const float* __restrict__ gc2, const float* __restrict__ bc2,
              const float* __restrict__ Wd, const float* __restrict__ bd,
              float* __restrict__ out, float* __restrict__ state,
              int t0, int nsteps)
{
    const int tid  = threadIdx.x;
    const int b    = blockIdx.x;
    const int lane = tid & 63;
    const int wav  = tid >> 6;

    __shared__ __align__(16) float zsA[256], zsB[256];
    __shared__ __align__(16) float h1p[4][UU], h2p[4][UU];
    __shared__ __align__(16) float h2hist[32 * 65];
    __shared__ __align__(16) float wds[UU * 16];
    __shared__ float bds[16];

    float* st = state + (size_t)b * 256;
    const int NS = nsteps;

    // ---- weights into registers (xgemm-proven idiom at this block shape) ----
    float w1h[UU], w2x[UU], w2h[UU];
    #pragma unroll
    for (int k = 0; k < UU; ++k) w1h[k] = W1[(DD + k) * 256 + tid];
    #pragma unroll
    for (int k = 0; k < UU; ++k) w2x[k] = W2[k * 256 + tid];
    #pragma unroll
    for (int k = 0; k < UU; ++k) w2h[k] = W2[(UU + k) * 256 + tid];

    const float g1 = gamma1[tid],  bb1 = beta1[tid];
    const float g2 = gamma2[tid],  bb2 = beta2[tid];
    const float gcl1 = gc1[lane],  bcl1 = bc1[lane];
    const float gcl2 = gc2[lane],  bcl2 = bc2[lane];

    for (int i = tid; i < UU * 16; i += 256) wds[i] = Wd[i];
    if (tid < 16) bds[tid] = bd[tid];

    float c1, c2, h1v, h2v;
    if (t0 == 0) { c1 = 0.f; c2 = 0.f; h1v = 0.f; h2v = 0.f; }
    else {
        c1 = st[lane];        h1v = st[64 + lane];
        c2 = st[128 + lane];  h2v = st[192 + lane];
    }
    h1p[wav][lane] = h1v;
    h2p[wav][lane] = h2v;
    // z2h = h2(prev) @ W2h, carried in a register across the loop.
    // Own-wave LDS write -> read: no barrier needed.
    float z2h = 0.f;
    if (t0 != 0) { DOT64(z2h, h2p[wav], w2h); }

    const float* zrow = z1x + (size_t)b * NS * 256;
    float zx = zrow[tid];
    __syncthreads();                           // init (wds/bds visibility)

    #pragma unroll 1
    for (int n = 0; n < NS; ++n) {
        float zxn = (n + 1 < NS) ? zrow[(size_t)(n + 1) * 256 + tid] : zx;

        // ---------- Phase A: z1 = z1x + h1 @ W1h, LN, gate act ----------
        float zdot;
        DOT64(zdot, h1p[wav], w1h);
        float z = zx + zdot;
        float s = wave_red_sum(z);
        float q = wave_red_sum(z * z);
        float mu  = s * (1.f/64.f);
        float var = q * (1.f/64.f) - mu * mu;
        float zn  = (z - mu) * __builtin_amdgcn_rsqf(var + 1e-12f) * g1 + bb1;
        zsA[tid] = (wav == 1) ? tanhfast(zn)
                 : (wav == 2) ? sigm(zn + 1.f)
                 :              sigm(zn);

        // batched output projection (reads h2hist rows n-18..n-3, all
        // written >= 2 barriers ago; slot n&31 not in the read set)
        if ((n & 15) == 2 && n >= 18) {
            int rloc = tid >> 4;
            int a    = tid & 15;
            int m    = n - 18 + rloc;
            float o = bds[a];
            const float* hrow = &h2hist[(m & 31) * 65];
            #pragma unroll
            for (int k = 0; k < UU; ++k)
                o = fmaf(hrow[k], wds[k * 16 + a], o);
            out[((size_t)b * TT + (t0 + m)) * 16 + a] = tanhfast(o);
        }
        __syncthreads();                       // B1

        // ---------- Phase B: cell 1 (all waves redundantly) ----------
        {
            float ai = zsA[lane],       aj = zsA[64 + lane];
            float af = zsA[128 + lane], ao = zsA[192 + lane];
            c1 = c1 * af + ai * aj;
            float cs = wave_red_sum(c1);
            float cq = wave_red_sum(c1 * c1);
            float cmu  = cs * (1.f/64.f);
            float cvar = cq * (1.f/64.f) - cmu * cmu;
            float cn   = (c1 - cmu) * __builtin_amdgcn_rsqf(cvar + 1e-12f) * gcl1 + bcl1;
            h1v = tanhfast(cn) * ao;
            h1p[wav][lane] = h1v;              // own-wave copy
        }
        // ---------- Phase C: z2 = h1 @ W2x + z2h, LN, act (no barrier:
        // z2x from own-wave h1p; z2h register-carried) ----------
        {
            float z2x;
            DOT64(z2x, h1p[wav], w2x);
            float z2 = z2x + z2h;
            float s2 = wave_red_sum(z2);
            float q2 = wave_red_sum(z2 * z2);
            float mu2  = s2 * (1.f/64.f);
            float var2 = q2 * (1.f/64.f) - mu2 * mu2;
            float zn2  = (z2 - mu2) * __builtin_amdgcn_rsqf(var2 + 1e-12f) * g2 + bb2;
            zsB[tid] = (wav == 1) ? tanhfast(zn2)
                     : (wav == 2) ? sigm(zn2 + 1.f)
                     :              sigm(zn2);
        }
        __syncthreads();                       // B2

        // ---------- Phase D: cell 2 (all waves redundantly) ----------
        {
            float ai = zsB[lane],       aj = zsB[64 + lane];
            float af = zsB[128 + lane], ao = zsB[192 + lane];
            c2 = c2 * af + ai * aj;
            float cs = wave_red_sum(c2);
            float cq = wave_red_sum(c2 * c2);
            float cmu  = cs * (1.f/64.f);
            float cvar = cq * (1.f/64.f) - cmu * cmu;
            float cn   = (c2 - cmu) * __builtin_amdgcn_rsqf(cvar + 1e-12f) * gcl2 + bcl2;
            h2v = tanhfast(cn) * ao;
            h2p[wav][lane] = h2v;              // own-wave copy
            if (wav == 0) h2hist[(n & 31) * 65 + lane] = h2v;
            DOT64(z2h, h2p[wav], w2h);         // z2h for step n+1
        }
        zx = zxn;
    }

    __syncthreads();                           // h2hist visibility for tail
    // epilogue projection: rows NS-16 .. NS-1
    {
        int rloc = tid >> 4;
        int a    = tid & 15;
        int m    = NS - 16 + rloc;
        float o = bds[a];
        const float* hrow = &h2hist[(m & 31) * 65];
        #pragma unroll
        for (int k = 0; k < UU; ++k)
            o = fmaf(hrow[k], wds[k * 16 + a], o);
        out[((size_t)b * TT + (t0 + m)) * 16 + a] = tanhfast(o);
    }

    if (t0 + NS < TT && wav == 0) {
        st[lane]       = c1;
        st[64 + lane]  = h1v;
        st[128 + lane] = c2;
        st[192 + lane] = h2v;
    }
}

extern "C" void kernel_launch(void* const* d_in, const int* in_sizes, int n_in,
                              void* d_out, int out_size, void* d_ws, size_t ws_size,
                              hipStream_t stream) {
    (void)in_sizes; (void)n_in; (void)out_size;
    const float* obss   = (const float*)d_in[0];
    const float* W1     = (const float*)d_in[1];
    const float* gamma1 = (const float*)d_in[2];
    const float* beta1  = (const float*)d_in[3];
    const float* gc1    = (const float*)d_in[4];
    const float* bc1    = (const float*)d_in[5];
    const float* W2     = (const float*)d_in[6];
    const float* gamma2 = (const float*)d_in[7];
    const float* beta2  = (const float*)d_in[8];
    const float* gc2    = (const float*)d_in[9];
    const float* bc2    = (const float*)d_in[10];
    const float* Wd     = (const float*)d_in[11];
    const float* bd     = (const float*)d_in[12];
    float* out = (float*)d_out;

    float* state = (float*)d_ws;
    float* z1x   = (float*)((char*)d_ws + (size_t)256 * 256 * sizeof(float));

    int CH = 16;
    for (int c = TT; c >= 16; c >>= 1) {
        size_t need = (size_t)256 * c * 256 * sizeof(float)
                    + (size_t)256 * 256 * sizeof(float);
        if (need <= ws_size) { CH = c; break; }
    }
    int chsh = 31 - __builtin_clz((unsigned)CH);

    for (int t0 = 0; t0 < TT; t0 += CH) {
        xgemm<<<(256 * CH) / 64, 256, 0, stream>>>(obss, W1, z1x, t0, chsh);
        lstm_rec<<<256, 256, 0, stream>>>(z1x, W1, W2,
                                          gamma1, beta1, gc1, bc1,
                                          gamma2, beta2, gc2, bc2,
                                          Wd, bd, out, state, t0, CH);
    }
}

// Round 19
// 1553.542 us; speedup vs baseline: 1.2830x; 1.2830x over previous
//
#include <hip/hip_runtime.h>
#include <math.h>

#define TT 1024
#define DD 128
#define UU 64

__device__ __forceinline__ float sigm(float x) {
    return __builtin_amdgcn_rcpf(1.0f + __expf(-x));
}
__device__ __forceinline__ float tanhfast(float x) {
    float e = __expf(2.0f * x);
    return fmaf(-2.0f, __builtin_amdgcn_rcpf(e + 1.0f), 1.0f);
}

// DPP-based full-wave (64-lane) sum, result broadcast via readlane(63).
template<int CTRL>
__device__ __forceinline__ float dpp_add(float v) {
    return v + __int_as_float(__builtin_amdgcn_update_dpp(
        0, __float_as_int(v), CTRL, 0xf, 0xf, true));
}
__device__ __forceinline__ float wave_red_sum(float v) {
    v = dpp_add<0x111>(v);   // row_shr:1
    v = dpp_add<0x112>(v);   // row_shr:2
    v = dpp_add<0x114>(v);   // row_shr:4
    v = dpp_add<0x118>(v);   // row_shr:8
    v = dpp_add<0x142>(v);   // row_bcast:15
    v = dpp_add<0x143>(v);   // row_bcast:31
    return __int_as_float(__builtin_amdgcn_readlane(__float_as_int(v), 63));
}

// ---------------------------------------------------------------------------
// G1-only: 64 named weight "registers" (in practice L2-resident reloads --
// this is the one group deliberately left on the L2 pipe).
#define W_DECL \
    float w00,w01,w02,w03,w04,w05,w06,w07,w08,w09,w10,w11,w12,w13,w14,w15, \
          w16,w17,w18,w19,w20,w21,w22,w23,w24,w25,w26,w27,w28,w29,w30,w31, \
          w32,w33,w34,w35,w36,w37,w38,w39,w40,w41,w42,w43,w44,w45,w46,w47, \
          w48,w49,w50,w51,w52,w53,w54,w55,w56,w57,w58,w59,w60,w61,w62,w63;

#define WL4(X) \
    X(0,w00)  X(1,w01)  X(2,w02)  X(3,w03)  X(4,w04)  X(5,w05)  X(6,w06)  X(7,w07)  \
    X(8,w08)  X(9,w09)  X(10,w10) X(11,w11) X(12,w12) X(13,w13) X(14,w14) X(15,w15) \
    X(16,w16) X(17,w17) X(18,w18) X(19,w19) X(20,w20) X(21,w21) X(22,w22) X(23,w23) \
    X(24,w24) X(25,w25) X(26,w26) X(27,w27) X(28,w28) X(29,w29) X(30,w30) X(31,w31) \
    X(32,w32) X(33,w33) X(34,w34) X(35,w35) X(36,w36) X(37,w37) X(38,w38) X(39,w39) \
    X(40,w40) X(41,w41) X(42,w42) X(43,w43) X(44,w44) X(45,w45) X(46,w46) X(47,w47) \
    X(48,w48) X(49,w49) X(50,w50) X(51,w51) X(52,w52) X(53,w53) X(54,w54) X(55,w55) \
    X(56,w56) X(57,w57) X(58,w58) X(59,w59) X(60,w60) X(61,w61) X(62,w62) X(63,w63)

#define W_LD(K,W) W = WEXPR(K);
#define W_LOAD() WL4(W_LD)

// dot (G1): LDS h-vector broadcast float4 reads x named weights (L2 pipe)
#define GCH(I,Wa,Wb,Wc,Wd2) { float4 q = _hv4[I];                  \
    a0 = fmaf(q.x, Wa, a0); a1 = fmaf(q.y, Wb, a1);                \
    a2 = fmaf(q.z, Wc, a2); a3 = fmaf(q.w, Wd2, a3); }
#define DOTW(res, vptr) do {                                       \
    const float4* _hv4 = (const float4*)(vptr);                    \
    float a0 = 0.f, a1 = 0.f, a2 = 0.f, a3 = 0.f;                  \
    GCH(0,w00,w01,w02,w03)   GCH(1,w04,w05,w06,w07)                \
    GCH(2,w08,w09,w10,w11)   GCH(3,w12,w13,w14,w15)                \
    GCH(4,w16,w17,w18,w19)   GCH(5,w20,w21,w22,w23)                \
    GCH(6,w24,w25,w26,w27)   GCH(7,w28,w29,w30,w31)                \
    GCH(8,w32,w33,w34,w35)   GCH(9,w36,w37,w38,w39)                \
    GCH(10,w40,w41,w42,w43)  GCH(11,w44,w45,w46,w47)               \
    GCH(12,w48,w49,w50,w51)  GCH(13,w52,w53,w54,w55)               \
    GCH(14,w56,w57,w58,w59)  GCH(15,w60,w61,w62,w63)               \
    res = (a0 + a1) + (a2 + a3);                                   \
} while (0)

// dot (G0/G2): f32 weight planes in LDS (per-lane ds_read_b128, consecutive
// lanes -> consecutive 16B slots, conflict-free) x LDS h-vector BROADCAST
// float4 reads (wave-uniform address -> cheap broadcast, no readlane).
// Plane j holds weight rows 4j..4j+3 of this thread's column.
#define DOTP(res, vptr, WFP) do {                                  \
    const float4* _hv4 = (const float4*)(vptr);                    \
    float a0 = 0.f, a1 = 0.f, a2 = 0.f, a3 = 0.f;                  \
    _Pragma("unroll")                                              \
    for (int _j = 0; _j < 16; ++_j) {                              \
        float4 wq = (WFP)[_j * 256];                               \
        float4 hq = _hv4[_j];                                      \
        a0 = fmaf(hq.x, wq.x, a0);                                 \
        a1 = fmaf(hq.y, wq.y, a1);                                 \
        a2 = fmaf(hq.z, wq.z, a2);                                 \
        a3 = fmaf(hq.w, wq.w, a3);                                 \
    }                                                              \
    res = (a0 + a1) + (a2 + a3);                                   \
} while (0)

// ================= x-part GEMM (round-4 proven version) ======================
__global__ __launch_bounds__(256, 1)
void xgemm(const float* __restrict__ obss, const float* __restrict__ W1,
           float* __restrict__ z1x, int t0, int chsh)
{
    const int tid = threadIdx.x;
    const int CH = 1 << chsh;
    __shared__ __align__(16) float xs[64 * DD];

    const int rbase = blockIdx.x * 64;
    for (int i = tid; i < 64 * (DD / 4); i += 256) {
        int rr = i >> 5;
        int k4 = i & 31;
        int r  = rbase + rr;
        int b  = r >> chsh;
        int tl = r & (CH - 1);
        ((float4*)xs)[rr * 32 + k4] =
            ((const float4*)(obss + ((size_t)b * TT + t0 + tl) * DD))[k4];
    }

    float w[DD];
    #pragma unroll
    for (int k = 0; k < DD; ++k) w[k] = W1[k * 256 + tid];
    __syncthreads();

    for (int rr = 0; rr < 64; rr += 2) {
        float a0=0,a1=0,a2=0,a3=0, b0=0,b1=0,b2=0,b3=0;
        const float4* x0 = (const float4*)(xs + rr * DD);
        const float4* x1 = (const float4*)(xs + (rr + 1) * DD);
        #pragma unroll
        for (int k4 = 0; k4 < DD / 4; ++k4) {
            float4 xv = x0[k4], yv = x1[k4];
            a0 = fmaf(xv.x, w[4*k4+0], a0);
            a1 = fmaf(xv.y, w[4*k4+1], a1);
            a2 = fmaf(xv.z, w[4*k4+2], a2);
            a3 = fmaf(xv.w, w[4*k4+3], a3);
            b0 = fmaf(yv.x, w[4*k4+0], b0);
            b1 = fmaf(yv.y, w[4*k4+1], b1);
            b2 = fmaf(yv.z, w[4*k4+2], b2);
            b3 = fmaf(yv.w, w[4*k4+3], b3);
        }
        size_t r = (size_t)rbase + rr;
        z1x[r * 256 + tid]       = (a0 + a1) + (a2 + a3);
        z1x[(r + 1) * 256 + tid] = (b0 + b1) + (b2 + b3);
    }
}

// ============ recurrent kernel: 3-group pipeline, 768 threads ================
// Pipe-balanced weight streams (R18 post-mortem: all-L2 = XCD-L2-bound at
// ~3400cy/step since 32 CUs share one L2 and each re-streams the same 192 KB
// per step): W1h (G0) + W2h (G2) as f32 float4-planes in LDS (128 KB, 16
// ds_read_b128/dot); W2x (G1) stays on L2 (64 KB/step); h via wave-uniform
// LDS broadcast everywhere (R17's readlane VALU cost removed).
__global__ __launch_bounds__(768) __attribute__((amdgpu_waves_per_eu(3, 3)))
void lstm_rec(const float* __restrict__ z1x,
              const float* __restrict__ W1, const float* __restrict__ W2,
              const float* __restrict__ gamma1, const float* __restrict__ beta1,
              const float* __restrict__ gc1, const float* __restrict__ bc1,
              const float* __restrict__ gamma2, const float* __restrict__ beta2,
              const float* __restrict__ gc2, const float* __restrict__ bc2,
              const float* __restrict__ Wd, const float* __restrict__ bd,
              float* __restrict__ out, float* __restrict__ state,
              int t0, int nsteps)
{
    const int tid  = threadIdx.x;
    const int b    = blockIdx.x;
    const int gid  = tid >> 8;        // 0, 1, 2
    const int stid = tid & 255;
    const int lane = stid & 63;
    const int wav  = stid >> 6;

    __shared__ __align__(16) float zsA[256], zsB[256], z2xs[256];
    __shared__ __align__(16) float h1ring[2][UU];
    __shared__ __align__(16) float h1p[4][UU], h2p[4][UU];
    __shared__ __align__(16) float h2hist[32 * 65];
    __shared__ __align__(16) float wds[UU * 16];
    __shared__ float bds[16];
    // f32 weight planes: [m*4096 + j*256 + col] = rows 4j..4j+3 of column col.
    // m=0: W1h (W1 rows 128..191), m=1: W2h (W2 rows 64..127). 128 KB.
    __shared__ __align__(16) float4 wf4[2 * 16 * 256];

    float* st = state + (size_t)b * 256;
    const int NS = nsteps;

    // ---- one-time staging: f32 global -> f32 LDS planes ----
    for (int i = tid; i < 2 * 16 * 256; i += 768) {
        int m   = i >> 12;
        int r   = i & 4095;
        int j   = r >> 8;
        int col = r & 255;
        const float* src = (m == 0) ? &W1[(DD + 4 * j) * 256 + col]
                                    : &W2[(UU + 4 * j) * 256 + col];
        wf4[i] = make_float4(src[0], src[256], src[512], src[768]);
    }

    if (gid == 0) {
        // ============================ G0: LAYER 1 ===========================
        const float4* wfp = &wf4[stid];            // W1h planes
        const float g1 = gamma1[stid], bb1 = beta1[stid];
        const float gcl = gc1[lane],  bcl = bc1[lane];

        float c1, h1v = 0.f;
        if (t0 == 0) { c1 = 0.f; h1p[wav][lane] = 0.f; }
        else         { c1 = st[lane]; h1v = st[64 + lane]; h1p[wav][lane] = h1v; }

        const float* zrow = z1x + (size_t)b * NS * 256;
        float zx = zrow[stid];
        __syncthreads();                       // init (covers weight staging)

        #pragma unroll 1
        for (int n = 0; n <= NS + 2; ++n) {
            float zxn = zx;
            if (n < NS) {
                int tnl = (n + 1 < NS) ? n + 1 : n;
                zxn = zrow[(size_t)tnl * 256 + stid];

                float zdot;
                DOTP(zdot, h1p[wav], wfp);
                float z = zx + zdot;
                float s = wave_red_sum(z);
                float q = wave_red_sum(z * z);
                float mu  = s * (1.f/64.f);
                float var = q * (1.f/64.f) - mu * mu;
                float zn  = (z - mu) * __builtin_amdgcn_rsqf(var + 1e-12f) * g1 + bb1;
                zsA[stid] = (wav == 1) ? tanhfast(zn)
                          : (wav == 2) ? sigm(zn + 1.f)
                          :              sigm(zn);
            }
            __syncthreads();                   // B1
            if (n < NS) {
                float ai = zsA[lane],       aj = zsA[64 + lane];
                float af = zsA[128 + lane], ao = zsA[192 + lane];
                c1 = c1 * af + ai * aj;
                float cs = wave_red_sum(c1);
                float cq = wave_red_sum(c1 * c1);
                float cmu  = cs * (1.f/64.f);
                float cvar = cq * (1.f/64.f) - cmu * cmu;
                float cn   = (c1 - cmu) * __builtin_amdgcn_rsqf(cvar + 1e-12f) * gcl + bcl;
                h1v = tanhfast(cn) * ao;
                h1p[wav][lane] = h1v;          // own-wave copy (no barrier RAW)
                if (wav == 0) h1ring[n & 1][lane] = h1v;
            }
            __syncthreads();                   // B2
            zx = zxn;
        }
        if (t0 + NS < TT && wav == 0) {
            st[lane]      = c1;
            st[64 + lane] = h1v;
        }
    } else if (gid == 1) {
        // ================= G1: z2x feed + output projection =================
        W_DECL
        #define WEXPR(K) (W2[(K) * 256 + stid])
        W_LOAD()
        #undef WEXPR
        for (int i = stid; i < UU * 16; i += 256) wds[i] = Wd[i];
        if (stid < 16) bds[stid] = bd[stid];
        __syncthreads();                       // init

        #pragma unroll 1
        for (int n = 0; n <= NS + 2; ++n) {
            if (n >= 1 && n <= NS) {
                float zxdot;
                DOTW(zxdot, h1ring[(n - 1) & 1]);
                z2xs[stid] = zxdot;
            }
            __syncthreads();                   // B1
            if ((n & 15) == 2 && n >= 18) {
                int rloc = stid >> 4;
                int a    = stid & 15;
                int m    = n - 18 + rloc;          // row within chunk
                float o = bds[a];
                const float* hrow = &h2hist[(m & 31) * 65];
                #pragma unroll
                for (int k = 0; k < UU; ++k)
                    o = fmaf(hrow[k], wds[k * 16 + a], o);
                out[((size_t)b * TT + (t0 + m)) * 16 + a] = tanhfast(o);
            }
            __syncthreads();                   // B2
        }
    } else {
        // ============================ G2: LAYER 2 ===========================
        const float4* wfp = &wf4[4096 + stid];     // W2h planes
        const float g2 = gamma2[stid], bb2 = beta2[stid];
        const float gcl = gc2[lane],  bcl = bc2[lane];

        float c2, h2v = 0.f;
        if (t0 == 0) { c2 = 0.f; h2p[wav][lane] = 0.f; }
        else         { c2 = st[128 + lane]; h2v = st[192 + lane]; h2p[wav][lane] = h2v; }
        __syncthreads();                       // init (weights now in LDS)
        // z2h carried in-register; recomputed at chunk start AFTER the barrier
        float z2h = 0.f;
        if (t0 != 0) { DOTP(z2h, h2p[wav], wfp); }

        #pragma unroll 1
        for (int n = 0; n <= NS + 2; ++n) {
            if (n >= 2 && n <= NS + 1) {
                // cell2 for step n-2 (zsB written p2(n-1), crosses B2)
                float ai = zsB[lane],       aj = zsB[64 + lane];
                float af = zsB[128 + lane], ao = zsB[192 + lane];
                c2 = c2 * af + ai * aj;
                float cs = wave_red_sum(c2);
                float cq = wave_red_sum(c2 * c2);
                float cmu  = cs * (1.f/64.f);
                float cvar = cq * (1.f/64.f) - cmu * cmu;
                float cn   = (c2 - cmu) * __builtin_amdgcn_rsqf(cvar + 1e-12f) * gcl + bcl;
                h2v = tanhfast(cn) * ao;
                h2p[wav][lane] = h2v;          // own-wave copy
                if (wav == 0) h2hist[((n - 2) & 31) * 65 + lane] = h2v;
                DOTP(z2h, h2p[wav], wfp);      // z2h for step n-1
            }
            __syncthreads();                   // B1
            if (n >= 1 && n <= NS) {
                float z2 = z2xs[stid] + z2h;
                float s2 = wave_red_sum(z2);
                float q2 = wave_red_sum(z2 * z2);
                float mu2  = s2 * (1.f/64.f);
                float var2 = q2 * (1.f/64.f) - mu2 * mu2;
                float zn2  = (z2 - mu2) * __builtin_amdgcn_rsqf(var2 + 1e-12f) * g2 + bb2;
                zsB[stid] = (wav == 1) ? tanhfast(zn2)
                          : (wav == 2) ? sigm(zn2 + 1.f)
                          :              sigm(zn2);
            }
            __syncthreads();                   // B2
        }
        if (t0 + NS < TT && wav == 0) {
            st[128 + lane] = c2;
            st[192 + lane] = h2v;
        }
    }
}

extern "C" void kernel_launch(void* const* d_in, const int* in_sizes, int n_in,
                              void* d_out, int out_size, void* d_ws, size_t ws_size,
                              hipStream_t stream) {
    (void)in_sizes; (void)n_in; (void)out_size;
    const float* obss   = (const float*)d_in[0];
    const float* W1     = (const float*)d_in[1];
    const float* gamma1 = (const float*)d_in[2];
    const float* beta1  = (const float*)d_in[3];
    const float* gc1    = (const float*)d_in[4];
    const float* bc1    = (const float*)d_in[5];
    const float* W2     = (const float*)d_in[6];
    const float* gamma2 = (const float*)d_in[7];
    const float* beta2  = (const float*)d_in[8];
    const float* gc2    = (const float*)d_in[9];
    const float* bc2    = (const float*)d_in[10];
    const float* Wd     = (const float*)d_in[11];
    const float* bd     = (const float*)d_in[12];
    float* out = (float*)d_out;

    float* state = (float*)d_ws;
    float* z1x   = (float*)((char*)d_ws + (size_t)256 * 256 * sizeof(float));

    int CH = 16;
    for (int c = TT; c >= 16; c >>= 1) {
        size_t need = (size_t)256 * c * 256 * sizeof(float)
                    + (size_t)256 * 256 * sizeof(float);
        if (need <= ws_size) { CH = c; break; }
    }
    int chsh = 31 - __builtin_clz((unsigned)CH);

    for (int t0 = 0; t0 < TT; t0 += CH) {
        xgemm<<<(256 * CH) / 64, 256, 0, stream>>>(obss, W1, z1x, t0, chsh);
        lstm_rec<<<256, 768, 0, stream>>>(z1x, W1, W2,
                                          gamma1, beta1, gc1, bc1,
                                          gamma2, beta2, gc2, bc2,
                                          Wd, bd, out, state, t0, CH);
    }
}

// Round 20
// 1324.974 us; speedup vs baseline: 1.5043x; 1.1725x over previous
//
#include <hip/hip_runtime.h>
#include <math.h>

#define TT 1024
#define DD 128
#define UU 64

__device__ __forceinline__ float sigm(float x) {
    return __builtin_amdgcn_rcpf(1.0f + __expf(-x));
}
__device__ __forceinline__ float tanhfast(float x) {
    float e = __expf(2.0f * x);
    return fmaf(-2.0f, __builtin_amdgcn_rcpf(e + 1.0f), 1.0f);
}

// DPP-based full-wave (64-lane) sum, result broadcast via readlane(63).
template<int CTRL>
__device__ __forceinline__ float dpp_add(float v) {
    return v + __int_as_float(__builtin_amdgcn_update_dpp(
        0, __float_as_int(v), CTRL, 0xf, 0xf, true));
}
__device__ __forceinline__ float wave_red_sum(float v) {
    v = dpp_add<0x111>(v);   // row_shr:1
    v = dpp_add<0x112>(v);   // row_shr:2
    v = dpp_add<0x114>(v);   // row_shr:4
    v = dpp_add<0x118>(v);   // row_shr:8
    v = dpp_add<0x142>(v);   // row_bcast:15
    v = dpp_add<0x143>(v);   // row_bcast:31
    return __int_as_float(__builtin_amdgcn_readlane(__float_as_int(v), 63));
}

// ---------------------------------------------------------------------------
// 64 named per-thread weight values (R13 configuration: measured optimum).
#define W_DECL \
    float w00,w01,w02,w03,w04,w05,w06,w07,w08,w09,w10,w11,w12,w13,w14,w15, \
          w16,w17,w18,w19,w20,w21,w22,w23,w24,w25,w26,w27,w28,w29,w30,w31, \
          w32,w33,w34,w35,w36,w37,w38,w39,w40,w41,w42,w43,w44,w45,w46,w47, \
          w48,w49,w50,w51,w52,w53,w54,w55,w56,w57,w58,w59,w60,w61,w62,w63;

// X(k, name, acc)
#define WL4(X) \
    X(0,w00,a0)  X(1,w01,a1)  X(2,w02,a2)  X(3,w03,a3)  \
    X(4,w04,a0)  X(5,w05,a1)  X(6,w06,a2)  X(7,w07,a3)  \
    X(8,w08,a0)  X(9,w09,a1)  X(10,w10,a2) X(11,w11,a3) \
    X(12,w12,a0) X(13,w13,a1) X(14,w14,a2) X(15,w15,a3) \
    X(16,w16,a0) X(17,w17,a1) X(18,w18,a2) X(19,w19,a3) \
    X(20,w20,a0) X(21,w21,a1) X(22,w22,a2) X(23,w23,a3) \
    X(24,w24,a0) X(25,w25,a1) X(26,w26,a2) X(27,w27,a3) \
    X(28,w28,a0) X(29,w29,a1) X(30,w30,a2) X(31,w31,a3) \
    X(32,w32,a0) X(33,w33,a1) X(34,w34,a2) X(35,w35,a3) \
    X(36,w36,a0) X(37,w37,a1) X(38,w38,a2) X(39,w39,a3) \
    X(40,w40,a0) X(41,w41,a1) X(42,w42,a2) X(43,w43,a3) \
    X(44,w44,a0) X(45,w45,a1) X(46,w46,a2) X(47,w47,a3) \
    X(48,w48,a0) X(49,w49,a1) X(50,w50,a2) X(51,w51,a3) \
    X(52,w52,a0) X(53,w53,a1) X(54,w54,a2) X(55,w55,a3) \
    X(56,w56,a0) X(57,w57,a1) X(58,w58,a2) X(59,w59,a3) \
    X(60,w60,a0) X(61,w61,a1) X(62,w62,a2) X(63,w63,a3)

#define W_LD(K,W,A) W = WEXPR(K);
#define W_LOAD() WL4(W_LD)

#define OPQ8(A,B,C,D,E,F,G,H) \
    asm("" : "+v"(A),"+v"(B),"+v"(C),"+v"(D),"+v"(E),"+v"(F),"+v"(G),"+v"(H));
#define W_OPAQUE() \
    OPQ8(w00,w01,w02,w03,w04,w05,w06,w07) \
    OPQ8(w08,w09,w10,w11,w12,w13,w14,w15) \
    OPQ8(w16,w17,w18,w19,w20,w21,w22,w23) \
    OPQ8(w24,w25,w26,w27,w28,w29,w30,w31) \
    OPQ8(w32,w33,w34,w35,w36,w37,w38,w39) \
    OPQ8(w40,w41,w42,w43,w44,w45,w46,w47) \
    OPQ8(w48,w49,w50,w51,w52,w53,w54,w55) \
    OPQ8(w56,w57,w58,w59,w60,w61,w62,w63)

// readlane: wave-uniform h[k] (VALU/SALU path -- NOT the LDS pipe)
#define RLF(H,K) __int_as_float(__builtin_amdgcn_readlane(__float_as_int(H), K))
#define FMRL(K,W,A) A = fmaf(RLF(_H,K), W, A);

// dot of wave-held vector (lane k holds v[k]) x 64 register weights
#define DOTRL(res, HS) do {                                        \
    float _H = (HS);                                               \
    float a0 = 0.f, a1 = 0.f, a2 = 0.f, a3 = 0.f;                  \
    WL4(FMRL)                                                      \
    res = (a0 + a1) + (a2 + a3);                                   \
} while (0)

// G1 dot: LDS h-vector (b128 broadcast reads) x 64 register weights
#define GCH(I,Wa,Wb,Wc,Wd2) { float4 q = _hv4[I];                  \
    a0 = fmaf(q.x, Wa, a0); a1 = fmaf(q.y, Wb, a1);                \
    a2 = fmaf(q.z, Wc, a2); a3 = fmaf(q.w, Wd2, a3); }
#define DOTLDS(res, vptr) do {                                     \
    const float4* _hv4 = (const float4*)(vptr);                    \
    float a0 = 0.f, a1 = 0.f, a2 = 0.f, a3 = 0.f;                  \
    GCH(0,w00,w01,w02,w03)   GCH(1,w04,w05,w06,w07)                \
    GCH(2,w08,w09,w10,w11)   GCH(3,w12,w13,w14,w15)                \
    GCH(4,w16,w17,w18,w19)   GCH(5,w20,w21,w22,w23)                \
    GCH(6,w24,w25,w26,w27)   GCH(7,w28,w29,w30,w31)                \
    GCH(8,w32,w33,w34,w35)   GCH(9,w36,w37,w38,w39)                \
    GCH(10,w40,w41,w42,w43)  GCH(11,w44,w45,w46,w47)               \
    GCH(12,w48,w49,w50,w51)  GCH(13,w52,w53,w54,w55)               \
    GCH(14,w56,w57,w58,w59)  GCH(15,w60,w61,w62,w63)               \
    res = (a0 + a1) + (a2 + a3);                                   \
} while (0)

// ================= x-part GEMM (round-4 proven version) ======================
__global__ __launch_bounds__(256, 1)
void xgemm(const float* __restrict__ obss, const float* __restrict__ W1,
           float* __restrict__ z1x, int t0, int chsh)
{
    const int tid = threadIdx.x;
    const int CH = 1 << chsh;
    __shared__ __align__(16) float xs[64 * DD];

    const int rbase = blockIdx.x * 64;
    for (int i = tid; i < 64 * (DD / 4); i += 256) {
        int rr = i >> 5;
        int k4 = i & 31;
        int r  = rbase + rr;
        int b  = r >> chsh;
        int tl = r & (CH - 1);
        ((float4*)xs)[rr * 32 + k4] =
            ((const float4*)(obss + ((size_t)b * TT + t0 + tl) * DD))[k4];
    }

    float w[DD];
    #pragma unroll
    for (int k = 0; k < DD; ++k) w[k] = W1[k * 256 + tid];
    __syncthreads();

    for (int rr = 0; rr < 64; rr += 2) {
        float a0=0,a1=0,a2=0,a3=0, b0=0,b1=0,b2=0,b3=0;
        const float4* x0 = (const float4*)(xs + rr * DD);
        const float4* x1 = (const float4*)(xs + (rr + 1) * DD);
        #pragma unroll
        for (int k4 = 0; k4 < DD / 4; ++k4) {
            float4 xv = x0[k4], yv = x1[k4];
            a0 = fmaf(xv.x, w[4*k4+0], a0);
            a1 = fmaf(xv.y, w[4*k4+1], a1);
            a2 = fmaf(xv.z, w[4*k4+2], a2);
            a3 = fmaf(xv.w, w[4*k4+3], a3);
            b0 = fmaf(yv.x, w[4*k4+0], b0);
            b1 = fmaf(yv.y, w[4*k4+1], b1);
            b2 = fmaf(yv.z, w[4*k4+2], b2);
            b3 = fmaf(yv.w, w[4*k4+3], b3);
        }
        size_t r = (size_t)rbase + rr;
        z1x[r * 256 + tid]       = (a0 + a1) + (a2 + a3);
        z1x[(r + 1) * 256 + tid] = (b0 + b1) + (b2 + b3);
    }
}

// ============ recurrent kernel: 3-group pipeline, 768 threads ================
// R13 configuration (measured optimum of the 10-variant grid, 1170us):
// G0/G2 dots read h via readlane from redundantly computed per-lane cell
// values (VALU pipe); weights stream from L1/L2; G1's dot via LDS b128.
__global__ __launch_bounds__(768) __attribute__((amdgpu_waves_per_eu(3, 3)))
void lstm_rec(const float* __restrict__ z1x,
              const float* __restrict__ W1, const float* __restrict__ W2,
              const float* __restrict__ gamma1, const float* __restrict__ beta1,
              const float* __restrict__ gc1, const float* __restrict__ bc1,
              const float* __restrict__ gamma2, const float* __restrict__ beta2,
              const float* __restrict__ gc2, const float* __restrict__ bc2,
              const float* __restrict__ Wd, const float* __restrict__ bd,
              float* __restrict__ out, float* __restrict__ state,
              int t0, int nsteps)
{
    const int tid  = threadIdx.x;
    const int b    = blockIdx.x;
    const int gid  = tid >> 8;        // 0, 1, 2
    const int stid = tid & 255;
    const int lane = stid & 63;
    const int wav  = stid >> 6;

    __shared__ __align__(16) float zsA[256], zsB[256], z2xs[256];
    __shared__ __align__(16) float h1ring[2][UU];
    __shared__ __align__(16) float h2hist[32 * 65];
    __shared__ __align__(16) float wds[UU * 16];
    __shared__ float bds[16];

    float* st = state + (size_t)b * 256;
    const int NS = nsteps;

    if (gid == 0) {
        // ============================ G0: LAYER 1 ===========================
        W_DECL
        #define WEXPR(K) (W1[(DD + (K)) * 256 + stid])
        W_LOAD()
        #undef WEXPR
        W_OPAQUE()
        const float g1 = gamma1[stid], bb1 = beta1[stid];
        const float gcl = gc1[lane],  bcl = bc1[lane];

        float c1, h1v;
        if (t0 == 0) { c1 = 0.f; h1v = 0.f; }
        else         { c1 = st[lane]; h1v = st[64 + lane]; }

        const float* zrow = z1x + (size_t)b * NS * 256;
        float zx = zrow[stid];
        __syncthreads();                       // init

        #pragma unroll 1
        for (int n = 0; n <= NS + 2; ++n) {
            float zxn = zx;
            if (n < NS) {
                int tnl = (n + 1 < NS) ? n + 1 : n;
                zxn = zrow[(size_t)tnl * 256 + stid];

                float zdot;
                DOTRL(zdot, h1v);              // h1 from own lanes (readlane)
                float z = zx + zdot;
                float s = wave_red_sum(z);
                float q = wave_red_sum(z * z);
                float mu  = s * (1.f/64.f);
                float var = q * (1.f/64.f) - mu * mu;
                float zn  = (z - mu) * __builtin_amdgcn_rsqf(var + 1e-12f) * g1 + bb1;
                zsA[stid] = (wav == 1) ? tanhfast(zn)
                          : (wav == 2) ? sigm(zn + 1.f)
                          :              sigm(zn);
            }
            __syncthreads();                   // B1
            if (n < NS) {
                float ai = zsA[lane],       aj = zsA[64 + lane];
                float af = zsA[128 + lane], ao = zsA[192 + lane];
                c1 = c1 * af + ai * aj;
                float cs = wave_red_sum(c1);
                float cq = wave_red_sum(c1 * c1);
                float cmu  = cs * (1.f/64.f);
                float cvar = cq * (1.f/64.f) - cmu * cmu;
                float cn   = (c1 - cmu) * __builtin_amdgcn_rsqf(cvar + 1e-12f) * gcl + bcl;
                h1v = tanhfast(cn) * ao;       // every wave holds h1 (lane=unit)
                if (wav == 0) h1ring[n & 1][lane] = h1v;
            }
            __syncthreads();                   // B2
            zx = zxn;
        }
        if (t0 + NS < TT && wav == 0) {
            st[lane]      = c1;
            st[64 + lane] = h1v;
        }
    } else if (gid == 1) {
        // ================= G1: z2x feed + output projection =================
        W_DECL
        #define WEXPR(K) (W2[(K) * 256 + stid])
        W_LOAD()
        #undef WEXPR
        W_OPAQUE()
        for (int i = stid; i < UU * 16; i += 256) wds[i] = Wd[i];
        if (stid < 16) bds[stid] = bd[stid];
        __syncthreads();                       // init

        #pragma unroll 1
        for (int n = 0; n <= NS + 2; ++n) {
            if (n >= 1 && n <= NS) {
                float zxdot;
                DOTLDS(zxdot, h1ring[(n - 1) & 1]);
                z2xs[stid] = zxdot;
            }
            __syncthreads();                   // B1
            if ((n & 15) == 2 && n >= 18) {
                int rloc = stid >> 4;
                int a    = stid & 15;
                int m    = n - 18 + rloc;          // row within chunk
                float o = bds[a];
                const float* hrow = &h2hist[(m & 31) * 65];
                #pragma unroll
                for (int k = 0; k < UU; ++k)
                    o = fmaf(hrow[k], wds[k * 16 + a], o);
                out[((size_t)b * TT + (t0 + m)) * 16 + a] = tanhfast(o);
            }
            __syncthreads();                   // B2
        }
    } else {
        // ============================ G2: LAYER 2 ===========================
        W_DECL
        #define WEXPR(K) (W2[(UU + (K)) * 256 + stid])
        W_LOAD()
        #undef WEXPR
        W_OPAQUE()
        const float g2 = gamma2[stid], bb2 = beta2[stid];
        const float gcl = gc2[lane],  bcl = bc2[lane];

        float c2, h2v;
        if (t0 == 0) { c2 = 0.f; h2v = 0.f; }
        else         { c2 = st[128 + lane]; h2v = st[192 + lane]; }
        // z2h carried in-register; recomputed from restored h2 (readlane path)
        float z2h = 0.f;
        if (t0 != 0) { DOTRL(z2h, h2v); }
        __syncthreads();                       // init

        #pragma unroll 1
        for (int n = 0; n <= NS + 2; ++n) {
            if (n >= 2 && n <= NS + 1) {
                // cell2 for step n-2 (zsB written p2(n-1), crosses B2)
                float ai = zsB[lane],       aj = zsB[64 + lane];
                float af = zsB[128 + lane], ao = zsB[192 + lane];
                c2 = c2 * af + ai * aj;
                float cs = wave_red_sum(c2);
                float cq = wave_red_sum(c2 * c2);
                float cmu  = cs * (1.f/64.f);
                float cvar = cq * (1.f/64.f) - cmu * cmu;
                float cn   = (c2 - cmu) * __builtin_amdgcn_rsqf(cvar + 1e-12f) * gcl + bcl;
                h2v = tanhfast(cn) * ao;       // every wave holds h2 (lane=unit)
                if (wav == 0) h2hist[((n - 2) & 31) * 65 + lane] = h2v;
                DOTRL(z2h, h2v);               // z2h for step n-1
            }
            __syncthreads();                   // B1
            if (n >= 1 && n <= NS) {
                float z2 = z2xs[stid] + z2h;
                float s2 = wave_red_sum(z2);
                float q2 = wave_red_sum(z2 * z2);
                float mu2  = s2 * (1.f/64.f);
                float var2 = q2 * (1.f/64.f) - mu2 * mu2;
                float zn2  = (z2 - mu2) * __builtin_amdgcn_rsqf(var2 + 1e-12f) * g2 + bb2;
                zsB[stid] = (wav == 1) ? tanhfast(zn2)
                          : (wav == 2) ? sigm(zn2 + 1.f)
                          :              sigm(zn2);
            }
            __syncthreads();                   // B2
        }
        if (t0 + NS < TT && wav == 0) {
            st[128 + lane] = c2;
            st[192 + lane] = h2v;
        }
    }
}

extern "C" void kernel_launch(void* const* d_in, const int* in_sizes, int n_in,
                              void* d_out, int out_size, void* d_ws, size_t ws_size,
                              hipStream_t stream) {
    (void)in_sizes; (void)n_in; (void)out_size;
    const float* obss   = (const float*)d_in[0];
    const float* W1     = (const float*)d_in[1];
    const float* gamma1 = (const float*)d_in[2];
    const float* beta1  = (const float*)d_in[3];
    const float* gc1    = (const float*)d_in[4];
    const float* bc1    = (const float*)d_in[5];
    const float* W2     = (const float*)d_in[6];
    const float* gamma2 = (const float*)d_in[7];
    const float* beta2  = (const float*)d_in[8];
    const float* gc2    = (const float*)d_in[9];
    const float* bc2    = (const float*)d_in[10];
    const float* Wd     = (const float*)d_in[11];
    const float* bd     = (const float*)d_in[12];
    float* out = (float*)d_out;

    float* state = (float*)d_ws;
    float* z1x   = (float*)((char*)d_ws + (size_t)256 * 256 * sizeof(float));

    int CH = 16;
    for (int c = TT; c >= 16; c >>= 1) {
        size_t need = (size_t)256 * c * 256 * sizeof(float)
                    + (size_t)256 * 256 * sizeof(float);
        if (need <= ws_size) { CH = c; break; }
    }
    int chsh = 31 - __builtin_clz((unsigned)CH);

    for (int t0 = 0; t0 < TT; t0 += CH) {
        xgemm<<<(256 * CH) / 64, 256, 0, stream>>>(obss, W1, z1x, t0, chsh);
        lstm_rec<<<256, 768, 0, stream>>>(z1x, W1, W2,
                                          gamma1, beta1, gc1, bc1,
                                          gamma2, beta2, gc2, bc2,
                                          Wd, bd, out, state, t0, CH);
    }
}